// Round 2
// baseline (775.534 us; speedup 1.0000x reference)
//
#include <hip/hip_runtime.h>
#include <math.h>

// FeatureWeightNet: grid_sample(bilinear,border) -> group correlation (G=8) ->
// MLP(8->16->8->1) with per-batch BN stats -> sigmoid.
// R9: fix R8's register-spill catastrophe (VGPR 256, 311MB scratch writes).
//  - stats1 rebuilt on the moment-matrix identity: sum(y^2) = w0^T (sum s s^T) w0.
//    Accumulates 8 first moments + 36 second moments of s per thread — NO
//    weight reads, no LDS in the hot loop (~60 VGPR).
//  - stats2/final: 2 pixels/thread, per-pixel-pipeline (x1[2][16] is the only
//    fat live array; z consumed immediately). LDS float4 weight reads feed 2
//    pixels each. __launch_bounds__(256,4) guardrails VGPR <= 128.
//  - No atomics: per-block partials in ws (overlay dead featB); consumers
//    redundantly tree-reduce partials in their prologue. Still 5 dispatches.

constexpr int   Bc  = 2;
constexpr int   Cc  = 64;
constexpr int   Hc  = 256;
constexpr int   Wc  = 320;
constexpr int   NBc = 9;
constexpr int   HWc = Hc * Wc;            // 81920
constexpr int   NPIX = Bc * HWc;          // 163840
constexpr int   NPT  = Bc * NBc * HWc;    // 1474560 (= out_size)
constexpr float EPSV = 1e-5f;

constexpr int NBLK_S = NPIX / 32;         // 5120 sample blocks
constexpr int NB1    = 512;               // stats1 blocks
constexpr int NGRP2  = NPT / 512;         // 2880 groups of 512 px (2/thread)
constexpr int NB2    = 720;               // stats2 blocks (4 groups each)
constexpr int NBF    = 720;               // final blocks

// workspace layout in float units (~45 MB, unchanged)
constexpr size_t OFF_FEATB = 0;                               // NHWC bf16: NPIX*64 ushort
constexpr size_t OFF_SB    = OFF_FEATB + (size_t)NPIX * 32;   // s bf16: NPT*8 ushort
// partials overlay featB (featB dead once k_sample has run):
constexpr size_t OFF_P1    = 0;                               // NB1*64 floats (44 used)
constexpr size_t OFF_P2    = OFF_P1 + (size_t)NB1 * 64;       // NB2*16 floats

__device__ __forceinline__ unsigned short f2bf_rne(float v) {
  unsigned int u = __float_as_uint(v);
  unsigned int r = (u + 0x7fffu + ((u >> 16) & 1u)) >> 16;
  return (unsigned short)r;
}
__device__ __forceinline__ void unpack8(uint4 u, float f[8]) {
  f[0] = __uint_as_float(u.x << 16);
  f[1] = __uint_as_float(u.x & 0xffff0000u);
  f[2] = __uint_as_float(u.y << 16);
  f[3] = __uint_as_float(u.y & 0xffff0000u);
  f[4] = __uint_as_float(u.z << 16);
  f[5] = __uint_as_float(u.z & 0xffff0000u);
  f[6] = __uint_as_float(u.w << 16);
  f[7] = __uint_as_float(u.w & 0xffff0000u);
}
__device__ __forceinline__ float dot8(const float s[8], float4 wa, float4 wb) {
  return s[0] * wa.x + s[1] * wa.y + s[2] * wa.z + s[3] * wa.w +
         s[4] * wb.x + s[5] * wb.y + s[6] * wb.z + s[7] * wb.w;
}

// ---------------------------------------------------------------------------
// K0: NCHW fp32 -> NHWC bf16 transpose.
__global__ __launch_bounds__(256) void k_transpose(
    const float* __restrict__ feat, unsigned short* __restrict__ featB) {
  __shared__ float lds[64][65];
  const int tid  = threadIdx.x;
  const int b    = blockIdx.x / (HWc / 64);
  const int tile = blockIdx.x % (HWc / 64);
  const int hw0  = tile * 64;
  const int p    = tid & 63;
  const int ty   = tid >> 6;  // 0..3

  const float* src = feat + (size_t)b * Cc * HWc + hw0 + p;
#pragma unroll
  for (int c0 = 0; c0 < 64; c0 += 4) {
    lds[c0 + ty][p] = src[(size_t)(c0 + ty) * HWc];
  }
  __syncthreads();
  const int ch = tid & 63;
  unsigned short* dst = featB + ((size_t)b * HWc + hw0) * 64 + ch;
#pragma unroll
  for (int p0 = 0; p0 < 64; p0 += 4) {
    dst[(size_t)(p0 + ty) * 64] = f2bf_rne(lds[ch][p0 + ty]);
  }
}

// ---------------------------------------------------------------------------
// K1: grid sample + group correlation.  PURE gather kernel (R2 structure —
// proven 3.9 TB/s).  UNCHANGED.
__global__ __launch_bounds__(256) void k_sample(
    const float* __restrict__ grid, const unsigned short* __restrict__ featB,
    unsigned short* __restrict__ sOut) {
  const int tid = threadIdx.x;
  const int cid = blockIdx.x * 32 + (tid >> 3);  // pixel id in [0, NPIX)
  const int j   = tid & 7;                       // group
  const int b   = cid / HWc;
  const int hw  = cid - b * HWc;
  const int h   = hw / Wc;
  const int w   = hw - h * Wc;

  const uint4* fbAll = (const uint4*)featB;
  const uint4 ur = fbAll[(size_t)cid * 8 + j];
  float r[8];
  unpack8(ur, r);

  const uint4* fb = fbAll + (size_t)b * HWc * 8;

#pragma unroll 3
  for (int n = 0; n < NBc; ++n) {
    const size_t gi = ((((size_t)b * NBc + n) * Hc + h) * Wc + w) * 2;
    const float2 g2 = *(const float2*)(grid + gi);
    float ix = ((g2.x + 1.f) * (float)Wc - 1.f) * 0.5f;
    float iy = ((g2.y + 1.f) * (float)Hc - 1.f) * 0.5f;
    ix = fminf(fmaxf(ix, 0.f), (float)(Wc - 1));
    iy = fminf(fmaxf(iy, 0.f), (float)(Hc - 1));
    const float x0f = floorf(ix), y0f = floorf(iy);
    const float fx = ix - x0f, fy = iy - y0f;
    const int x0 = (int)x0f, y0 = (int)y0f;
    const int x1 = min(x0 + 1, Wc - 1), y1 = min(y0 + 1, Hc - 1);
    const float w00 = (1.f - fx) * (1.f - fy);
    const float w01 = fx * (1.f - fy);
    const float w10 = (1.f - fx) * fy;
    const float w11 = fx * fy;

    const uint4 u00 = fb[(size_t)(y0 * Wc + x0) * 8 + j];
    const uint4 u01 = fb[(size_t)(y0 * Wc + x1) * 8 + j];
    const uint4 u10 = fb[(size_t)(y1 * Wc + x0) * 8 + j];
    const uint4 u11 = fb[(size_t)(y1 * Wc + x1) * 8 + j];
    float a[8], c[8], d[8], e[8];
    unpack8(u00, a);
    unpack8(u01, c);
    unpack8(u10, d);
    unpack8(u11, e);

    float s = 0.f;
#pragma unroll
    for (int k = 0; k < 8; ++k) {
      s += (w00 * a[k] + w01 * c[k] + w10 * d[k] + w11 * e[k]) * r[k];
    }
    s *= 0.125f;  // mean over C/G = 8

    const size_t pt = ((size_t)b * NBc + n) * HWc + hw;
    sOut[pt * 8 + j] = f2bf_rne(s);
  }
}

// ---------------------------------------------------------------------------
// K2: stats1 — moment matrix of s.  acc[0..7] = sum s_j; acc[8+tri(j,k)] =
// sum s_j*s_k (upper triangle, 36).  No weights, no LDS in hot loop.
__global__ __launch_bounds__(256, 4) void k_stats1(
    const unsigned short* __restrict__ sB, float* __restrict__ part1) {
  float acc[44];
#pragma unroll
  for (int i = 0; i < 44; ++i) acc[i] = 0.f;
  const int tid = threadIdx.x;
  const int stride = NB1 * 256;
  for (int p = blockIdx.x * 256 + tid; p < NPT; p += stride) {
    const uint4 su = ((const uint4*)sB)[p];
    float s[8];
    unpack8(su, s);
#pragma unroll
    for (int j = 0; j < 8; ++j) acc[j] += s[j];
#pragma unroll
    for (int j = 0; j < 8; ++j) {
#pragma unroll
      for (int k = 0; k <= j; ++k) {
        acc[8 + j * (j + 1) / 2 + k] += s[j] * s[k];
      }
    }
  }
  __shared__ float red[4 * 44];
  const int wid = tid >> 6;
#pragma unroll
  for (int i = 0; i < 44; ++i) {
    float v = acc[i];
#pragma unroll
    for (int off = 32; off; off >>= 1) v += __shfl_xor(v, off);
    if ((tid & 63) == 0) red[wid * 44 + i] = v;
  }
  __syncthreads();
  if (tid < 44) {
    part1[blockIdx.x * 64 + tid] =
        red[tid] + red[44 + tid] + red[88 + tid] + red[132 + tid];
  }
}

// ---------------------------------------------------------------------------
// K3: stats2 — prologue: reduce part1 -> moments -> bn1 (a1,c1).  Main:
// 2 px/thread pipeline; z/z^2 partials -> part2[NB2][16].
__global__ __launch_bounds__(256, 4) void k_stats2(
    const unsigned short* __restrict__ sB, const float* __restrict__ part1,
    const float* __restrict__ w0, const float* __restrict__ w1,
    const float* __restrict__ g0, const float* __restrict__ b0,
    float* __restrict__ part2) {
  __shared__ float w0s[128], w1s[128];
  __shared__ float2 a1c2[16];
  __shared__ float red[256];
  __shared__ float totm[64];
  const int tid = threadIdx.x;
  if (tid < 128) { w0s[tid] = w0[tid]; w1s[tid] = w1[tid]; }
  {  // reduce part1 (NB1 x 64, 44 used)
    const int col = tid & 63, chk = tid >> 6;
    float a = 0.f;
    for (int r = chk; r < NB1; r += 4) a += part1[r * 64 + col];
    red[tid] = a;
  }
  __syncthreads();
  if (tid < 64) totm[tid] = red[tid] + red[64 + tid] + red[128 + tid] + red[192 + tid];
  __syncthreads();
  if (tid < 16) {  // bn1 params from moments
    float wr[8];
    float mean = 0.f, ey2 = 0.f;
#pragma unroll
    for (int j = 0; j < 8; ++j) {
      wr[j] = w0s[tid * 8 + j];
      mean += wr[j] * totm[j];
    }
#pragma unroll
    for (int j = 0; j < 8; ++j) {
#pragma unroll
      for (int k = 0; k <= j; ++k) {
        const float v = wr[j] * wr[k] * totm[8 + j * (j + 1) / 2 + k];
        ey2 += (k == j) ? v : 2.f * v;
      }
    }
    const float invN = 1.f / (float)NPT;
    mean *= invN;
    ey2 *= invN;
    const float var = ey2 - mean * mean;
    const float a = g0[tid] * rsqrtf(var + EPSV);
    a1c2[tid] = make_float2(a, b0[tid] - mean * a);
  }
  __syncthreads();

  float sz[8], sz2[8];
#pragma unroll
  for (int o = 0; o < 8; ++o) { sz[o] = 0.f; sz2[o] = 0.f; }

  for (int g = blockIdx.x; g < NGRP2; g += NB2) {
    const uint4* src = (const uint4*)sB + (size_t)g * 512 + tid;
    const uint4 su0 = src[0];
    const uint4 su1 = src[256];
    float s0[8], s1[8];
    unpack8(su0, s0);
    unpack8(su1, s1);
    float x1a[16], x1b[16];
#pragma unroll
    for (int c = 0; c < 16; ++c) {
      const float4 wa = *(const float4*)(w0s + c * 8);
      const float4 wb = *(const float4*)(w0s + c * 8 + 4);
      const float2 ac = a1c2[c];
      x1a[c] = fmaxf(fmaf(ac.x, dot8(s0, wa, wb), ac.y), 0.f);
      x1b[c] = fmaxf(fmaf(ac.x, dot8(s1, wa, wb), ac.y), 0.f);
    }
#pragma unroll
    for (int o = 0; o < 8; ++o) {
      float z0 = 0.f, z1 = 0.f;
#pragma unroll
      for (int q = 0; q < 4; ++q) {
        const float4 wv = *(const float4*)(w1s + o * 16 + q * 4);
        z0 += x1a[q * 4 + 0] * wv.x + x1a[q * 4 + 1] * wv.y +
              x1a[q * 4 + 2] * wv.z + x1a[q * 4 + 3] * wv.w;
        z1 += x1b[q * 4 + 0] * wv.x + x1b[q * 4 + 1] * wv.y +
              x1b[q * 4 + 2] * wv.z + x1b[q * 4 + 3] * wv.w;
      }
      sz[o] += z0 + z1;
      sz2[o] += z0 * z0 + z1 * z1;
    }
  }
  const int wid = tid >> 6;
#pragma unroll
  for (int o = 0; o < 8; ++o) {
    float v = sz[o], v2 = sz2[o];
#pragma unroll
    for (int off = 32; off; off >>= 1) {
      v += __shfl_xor(v, off);
      v2 += __shfl_xor(v2, off);
    }
    if ((tid & 63) == 0) {
      red[wid * 16 + o] = v;
      red[wid * 16 + 8 + o] = v2;
    }
  }
  __syncthreads();
  if (tid < 16) {
    part2[blockIdx.x * 16 + tid] =
        red[tid] + red[16 + tid] + red[32 + tid] + red[48 + tid];
  }
}

// ---------------------------------------------------------------------------
// K4: final — prologue: bn1 from part1, bn2 from part2.  Main: 2 px/thread
// pipeline; full MLP + sigmoid -> out.
__global__ __launch_bounds__(256, 4) void k_final(
    const unsigned short* __restrict__ sB, const float* __restrict__ part1,
    const float* __restrict__ part2, const float* __restrict__ w0,
    const float* __restrict__ w1, const float* __restrict__ g0,
    const float* __restrict__ b0, const float* __restrict__ g1,
    const float* __restrict__ b1, const float* __restrict__ wsW,
    const float* __restrict__ bs, float* __restrict__ out) {
  __shared__ float w0s[128], w1s[128];
  __shared__ float2 a1c2[16];
  __shared__ float4 w2s[8];  // (a2, c2, ws, 0)
  __shared__ float red[256];
  __shared__ float totm[64];
  __shared__ float totz[16];
  __shared__ float bssS;
  const int tid = threadIdx.x;
  if (tid < 128) { w0s[tid] = w0[tid]; w1s[tid] = w1[tid]; }
  if (tid == 0) bssS = bs[0];
  {  // reduce part1
    const int col = tid & 63, chk = tid >> 6;
    float a = 0.f;
    for (int r = chk; r < NB1; r += 4) a += part1[r * 64 + col];
    red[tid] = a;
  }
  __syncthreads();
  if (tid < 64) totm[tid] = red[tid] + red[64 + tid] + red[128 + tid] + red[192 + tid];
  __syncthreads();
  if (tid < 16) {  // bn1
    float wr[8];
    float mean = 0.f, ey2 = 0.f;
#pragma unroll
    for (int j = 0; j < 8; ++j) {
      wr[j] = w0s[tid * 8 + j];
      mean += wr[j] * totm[j];
    }
#pragma unroll
    for (int j = 0; j < 8; ++j) {
#pragma unroll
      for (int k = 0; k <= j; ++k) {
        const float v = wr[j] * wr[k] * totm[8 + j * (j + 1) / 2 + k];
        ey2 += (k == j) ? v : 2.f * v;
      }
    }
    const float invN = 1.f / (float)NPT;
    mean *= invN;
    ey2 *= invN;
    const float var = ey2 - mean * mean;
    const float a = g0[tid] * rsqrtf(var + EPSV);
    a1c2[tid] = make_float2(a, b0[tid] - mean * a);
  }
  {  // reduce part2 (NB2 x 16)
    const int col = tid & 15, chk = tid >> 4;
    float a = 0.f;
    for (int r = chk; r < NB2; r += 16) a += part2[r * 16 + col];
    red[tid] = a;
  }
  __syncthreads();
  if (tid < 16) {
    float v = 0.f;
#pragma unroll
    for (int k = 0; k < 16; ++k) v += red[k * 16 + tid];
    totz[tid] = v;
  }
  __syncthreads();
  if (tid < 8) {  // bn2
    const float invN = 1.f / (float)NPT;
    const float mean = totz[tid] * invN;
    const float var = totz[8 + tid] * invN - mean * mean;
    const float a = g1[tid] * rsqrtf(var + EPSV);
    w2s[tid] = make_float4(a, b1[tid] - mean * a, wsW[tid], 0.f);
  }
  __syncthreads();

  const float bsr = bssS;
  for (int g = blockIdx.x; g < NGRP2; g += NBF) {
    const uint4* src = (const uint4*)sB + (size_t)g * 512 + tid;
    const uint4 su0 = src[0];
    const uint4 su1 = src[256];
    float s0[8], s1[8];
    unpack8(su0, s0);
    unpack8(su1, s1);
    float x1a[16], x1b[16];
#pragma unroll
    for (int c = 0; c < 16; ++c) {
      const float4 wa = *(const float4*)(w0s + c * 8);
      const float4 wb = *(const float4*)(w0s + c * 8 + 4);
      const float2 ac = a1c2[c];
      x1a[c] = fmaxf(fmaf(ac.x, dot8(s0, wa, wb), ac.y), 0.f);
      x1b[c] = fmaxf(fmaf(ac.x, dot8(s1, wa, wb), ac.y), 0.f);
    }
    float o0 = bsr, o1 = bsr;
#pragma unroll
    for (int o = 0; o < 8; ++o) {
      float z0 = 0.f, z1 = 0.f;
#pragma unroll
      for (int q = 0; q < 4; ++q) {
        const float4 wv = *(const float4*)(w1s + o * 16 + q * 4);
        z0 += x1a[q * 4 + 0] * wv.x + x1a[q * 4 + 1] * wv.y +
              x1a[q * 4 + 2] * wv.z + x1a[q * 4 + 3] * wv.w;
        z1 += x1b[q * 4 + 0] * wv.x + x1b[q * 4 + 1] * wv.y +
              x1b[q * 4 + 2] * wv.z + x1b[q * 4 + 3] * wv.w;
      }
      const float4 pr = w2s[o];
      o0 += pr.z * fmaxf(fmaf(pr.x, z0, pr.y), 0.f);
      o1 += pr.z * fmaxf(fmaf(pr.x, z1, pr.y), 0.f);
    }
    float* op = out + (size_t)g * 512 + tid;
    op[0]   = 1.f / (1.f + __expf(-o0));
    op[256] = 1.f / (1.f + __expf(-o1));
  }
}

// ---------------------------------------------------------------------------
extern "C" void kernel_launch(void* const* d_in, const int* in_sizes, int n_in,
                              void* d_out, int out_size, void* d_ws,
                              size_t ws_size, hipStream_t stream) {
  const float* feat = (const float*)d_in[0];  // [2,64,256,320]
  const float* grid = (const float*)d_in[1];  // [2,2304,320,2]
  const float* w0 = (const float*)d_in[2];    // [16,8]
  const float* g0 = (const float*)d_in[3];
  const float* b0 = (const float*)d_in[4];
  const float* w1 = (const float*)d_in[5];    // [8,16]
  const float* g1 = (const float*)d_in[6];
  const float* b1 = (const float*)d_in[7];
  const float* wsW = (const float*)d_in[8];   // [1,8]
  const float* bs = (const float*)d_in[9];    // [1]
  float* out = (float*)d_out;

  float* wsf = (float*)d_ws;  // ~45 MB
  unsigned short* featB = (unsigned short*)(wsf + OFF_FEATB);
  unsigned short* sB    = (unsigned short*)(wsf + OFF_SB);
  float* part1 = wsf + OFF_P1;  // overlays featB (dead after k_sample)
  float* part2 = wsf + OFF_P2;

  k_transpose<<<Bc * (HWc / 64), 256, 0, stream>>>(feat, featB);
  k_sample<<<NBLK_S, 256, 0, stream>>>(grid, featB, sB);
  k_stats1<<<NB1, 256, 0, stream>>>(sB, part1);
  k_stats2<<<NB2, 256, 0, stream>>>(sB, part1, w0, w1, g0, b0, part2);
  k_final<<<NBF, 256, 0, stream>>>(sB, part1, part2, w0, w1, g0, b0, g1, b1,
                                   wsW, bs, out);
}

// Round 3
// 434.162 us; speedup vs baseline: 1.7863x; 1.7863x over previous
//
#include <hip/hip_runtime.h>
#include <math.h>

// FeatureWeightNet: grid_sample(bilinear,border) -> group correlation (G=8) ->
// MLP(8->16->8->1) with per-batch BN stats -> sigmoid.
// R10: tail rebuilt after two spill failures (R8: 256 VGPR genuine spill;
// R9: __launch_bounds__(256,4) artificially capped 64 VGPR -> 1.1 GB scratch).
//  - NO min-waves launch_bounds anywhere. Pressure controlled by construction.
//  - stats2/final: incremental-z restructure kills the x1[16] live array:
//    for each c: x_c = relu(w0'[c]·s + c1[c]); z[i][o] += w1T[c][o]*x_c.
//    Live state at 4 px/thread: s[4][8] + z[4][8] ~= 110 VGPR.
//  - LDS weights read once per c per 4 pixels (broadcast), BN1 pre-folded
//    into w0' by the prologue.
//  - stats1: moment-matrix identity (sum y^2 = w0^T (sum s s^T) w0), no
//    weights, no LDS in hot loop.
//  - No atomics: per-block partials (NB1=NB2=360 rows) overlay dead featB;
//    consumers redundantly tree-reduce them in the prologue. 5 dispatches.

constexpr int   Bc  = 2;
constexpr int   Cc  = 64;
constexpr int   Hc  = 256;
constexpr int   Wc  = 320;
constexpr int   NBc = 9;
constexpr int   HWc = Hc * Wc;            // 81920
constexpr int   NPIX = Bc * HWc;          // 163840
constexpr int   NPT  = Bc * NBc * HWc;    // 1474560 (= out_size)
constexpr float EPSV = 1e-5f;

constexpr int NBLK_S = NPIX / 32;         // 5120 sample blocks
constexpr int NB1    = 360;               // stats1 blocks
constexpr int NGRP4  = NPT / 1024;        // 1440 groups of 1024 px (4/thread)
constexpr int NB2    = 360;               // stats2 blocks (4 groups each)
constexpr int NBF    = 480;               // final blocks (3 groups each)

// workspace layout in float units (~45 MB, unchanged)
constexpr size_t OFF_FEATB = 0;                               // NHWC bf16: NPIX*64 ushort
constexpr size_t OFF_SB    = OFF_FEATB + (size_t)NPIX * 32;   // s bf16: NPT*8 ushort
// partials overlay featB (featB dead once k_sample has run):
constexpr size_t OFF_P1    = 0;                               // NB1*64 floats (44 used)
constexpr size_t OFF_P2    = OFF_P1 + (size_t)NB1 * 64;       // NB2*16 floats

__device__ __forceinline__ unsigned short f2bf_rne(float v) {
  unsigned int u = __float_as_uint(v);
  unsigned int r = (u + 0x7fffu + ((u >> 16) & 1u)) >> 16;
  return (unsigned short)r;
}
__device__ __forceinline__ void unpack8(uint4 u, float f[8]) {
  f[0] = __uint_as_float(u.x << 16);
  f[1] = __uint_as_float(u.x & 0xffff0000u);
  f[2] = __uint_as_float(u.y << 16);
  f[3] = __uint_as_float(u.y & 0xffff0000u);
  f[4] = __uint_as_float(u.z << 16);
  f[5] = __uint_as_float(u.z & 0xffff0000u);
  f[6] = __uint_as_float(u.w << 16);
  f[7] = __uint_as_float(u.w & 0xffff0000u);
}
__device__ __forceinline__ float dot8(const float s[8], float4 wa, float4 wb) {
  return s[0] * wa.x + s[1] * wa.y + s[2] * wa.z + s[3] * wa.w +
         s[4] * wb.x + s[5] * wb.y + s[6] * wb.z + s[7] * wb.w;
}

// ---------------------------------------------------------------------------
// K0: NCHW fp32 -> NHWC bf16 transpose.
__global__ __launch_bounds__(256) void k_transpose(
    const float* __restrict__ feat, unsigned short* __restrict__ featB) {
  __shared__ float lds[64][65];
  const int tid  = threadIdx.x;
  const int b    = blockIdx.x / (HWc / 64);
  const int tile = blockIdx.x % (HWc / 64);
  const int hw0  = tile * 64;
  const int p    = tid & 63;
  const int ty   = tid >> 6;  // 0..3

  const float* src = feat + (size_t)b * Cc * HWc + hw0 + p;
#pragma unroll
  for (int c0 = 0; c0 < 64; c0 += 4) {
    lds[c0 + ty][p] = src[(size_t)(c0 + ty) * HWc];
  }
  __syncthreads();
  const int ch = tid & 63;
  unsigned short* dst = featB + ((size_t)b * HWc + hw0) * 64 + ch;
#pragma unroll
  for (int p0 = 0; p0 < 64; p0 += 4) {
    dst[(size_t)(p0 + ty) * 64] = f2bf_rne(lds[ch][p0 + ty]);
  }
}

// ---------------------------------------------------------------------------
// K1: grid sample + group correlation.  PURE gather kernel (R2 structure —
// proven 3.9 TB/s).  UNCHANGED.
__global__ __launch_bounds__(256) void k_sample(
    const float* __restrict__ grid, const unsigned short* __restrict__ featB,
    unsigned short* __restrict__ sOut) {
  const int tid = threadIdx.x;
  const int cid = blockIdx.x * 32 + (tid >> 3);  // pixel id in [0, NPIX)
  const int j   = tid & 7;                       // group
  const int b   = cid / HWc;
  const int hw  = cid - b * HWc;
  const int h   = hw / Wc;
  const int w   = hw - h * Wc;

  const uint4* fbAll = (const uint4*)featB;
  const uint4 ur = fbAll[(size_t)cid * 8 + j];
  float r[8];
  unpack8(ur, r);

  const uint4* fb = fbAll + (size_t)b * HWc * 8;

#pragma unroll 3
  for (int n = 0; n < NBc; ++n) {
    const size_t gi = ((((size_t)b * NBc + n) * Hc + h) * Wc + w) * 2;
    const float2 g2 = *(const float2*)(grid + gi);
    float ix = ((g2.x + 1.f) * (float)Wc - 1.f) * 0.5f;
    float iy = ((g2.y + 1.f) * (float)Hc - 1.f) * 0.5f;
    ix = fminf(fmaxf(ix, 0.f), (float)(Wc - 1));
    iy = fminf(fmaxf(iy, 0.f), (float)(Hc - 1));
    const float x0f = floorf(ix), y0f = floorf(iy);
    const float fx = ix - x0f, fy = iy - y0f;
    const int x0 = (int)x0f, y0 = (int)y0f;
    const int x1 = min(x0 + 1, Wc - 1), y1 = min(y0 + 1, Hc - 1);
    const float w00 = (1.f - fx) * (1.f - fy);
    const float w01 = fx * (1.f - fy);
    const float w10 = (1.f - fx) * fy;
    const float w11 = fx * fy;

    const uint4 u00 = fb[(size_t)(y0 * Wc + x0) * 8 + j];
    const uint4 u01 = fb[(size_t)(y0 * Wc + x1) * 8 + j];
    const uint4 u10 = fb[(size_t)(y1 * Wc + x0) * 8 + j];
    const uint4 u11 = fb[(size_t)(y1 * Wc + x1) * 8 + j];
    float a[8], c[8], d[8], e[8];
    unpack8(u00, a);
    unpack8(u01, c);
    unpack8(u10, d);
    unpack8(u11, e);

    float s = 0.f;
#pragma unroll
    for (int k = 0; k < 8; ++k) {
      s += (w00 * a[k] + w01 * c[k] + w10 * d[k] + w11 * e[k]) * r[k];
    }
    s *= 0.125f;  // mean over C/G = 8

    const size_t pt = ((size_t)b * NBc + n) * HWc + hw;
    sOut[pt * 8 + j] = f2bf_rne(s);
  }
}

// ---------------------------------------------------------------------------
// K2: stats1 — moment matrix of s.  acc[0..7] = sum s_j; acc[8+tri(j,k)] =
// sum s_j*s_k (36).  No weights, no LDS in hot loop.  ~60 live VGPR.
__global__ __launch_bounds__(256) void k_stats1(
    const unsigned short* __restrict__ sB, float* __restrict__ part1) {
  float acc[44];
#pragma unroll
  for (int i = 0; i < 44; ++i) acc[i] = 0.f;
  const int tid = threadIdx.x;
  const int stride = NB1 * 256;
  for (int p = blockIdx.x * 256 + tid; p < NPT; p += stride) {
    const uint4 su = ((const uint4*)sB)[p];
    float s[8];
    unpack8(su, s);
#pragma unroll
    for (int j = 0; j < 8; ++j) acc[j] += s[j];
#pragma unroll
    for (int j = 0; j < 8; ++j) {
#pragma unroll
      for (int k = 0; k <= j; ++k) {
        acc[8 + j * (j + 1) / 2 + k] += s[j] * s[k];
      }
    }
  }
  __shared__ float red[4 * 44];
  const int wid = tid >> 6;
#pragma unroll
  for (int i = 0; i < 44; ++i) {
    float v = acc[i];
#pragma unroll
    for (int off = 32; off; off >>= 1) v += __shfl_xor(v, off);
    if ((tid & 63) == 0) red[wid * 44 + i] = v;
  }
  __syncthreads();
  if (tid < 44) {
    part1[blockIdx.x * 64 + tid] =
        red[tid] + red[44 + tid] + red[88 + tid] + red[132 + tid];
  }
}

// ---------------------------------------------------------------------------
// shared prologue helper: reduce part1 -> totm[44], compute bn1 -> a1s/c1v,
// build premultiplied w0p (a1-folded) and transposed w1t in LDS.
__device__ __forceinline__ void tail_prologue(
    const float* __restrict__ part1, const float* __restrict__ w0,
    const float* __restrict__ w1, const float* __restrict__ g0,
    const float* __restrict__ b0, float* red, float* totm, float* a1s,
    float* c1v, float* w0p, float* w1t) {
  const int tid = threadIdx.x;
  {  // reduce part1 (NB1 x 64, 44 used)
    const int col = tid & 63, chk = tid >> 6;
    float a = 0.f;
    for (int r = chk; r < NB1; r += 4) a += part1[r * 64 + col];
    red[tid] = a;
  }
  __syncthreads();
  if (tid < 64)
    totm[tid] = red[tid] + red[64 + tid] + red[128 + tid] + red[192 + tid];
  __syncthreads();
  if (tid < 16) {  // bn1 params from moments
    float wr[8];
    float mean = 0.f, ey2 = 0.f;
#pragma unroll
    for (int j = 0; j < 8; ++j) {
      wr[j] = w0[tid * 8 + j];
      mean += wr[j] * totm[j];
    }
#pragma unroll
    for (int j = 0; j < 8; ++j) {
#pragma unroll
      for (int k = 0; k <= j; ++k) {
        const float v = wr[j] * wr[k] * totm[8 + j * (j + 1) / 2 + k];
        ey2 += (k == j) ? v : 2.f * v;
      }
    }
    const float invN = 1.f / (float)NPT;
    mean *= invN;
    ey2 *= invN;
    const float var = ey2 - mean * mean;
    const float a = g0[tid] * rsqrtf(var + EPSV);
    a1s[tid] = a;
    c1v[tid] = b0[tid] - mean * a;
  }
  __syncthreads();
  if (tid < 128) {
    w0p[tid] = a1s[tid >> 3] * w0[tid];           // a1-folded weights
    w1t[(tid & 15) * 8 + (tid >> 4)] = w1[tid];   // [o][c] -> [c][o]
  }
  __syncthreads();
}

// 4-pixel incremental-z MLP core: s[4][8] -> z[4][8] (post-relu layer1 folded)
__device__ __forceinline__ void mlp_core(const float s[4][8], float z[4][8],
                                         const float* w0p, const float* c1v,
                                         const float* w1t) {
#pragma unroll
  for (int i = 0; i < 4; ++i)
#pragma unroll
    for (int o = 0; o < 8; ++o) z[i][o] = 0.f;
#pragma unroll
  for (int c = 0; c < 16; ++c) {
    const float4 wa = *(const float4*)(w0p + c * 8);
    const float4 wb = *(const float4*)(w0p + c * 8 + 4);
    const float cc = c1v[c];
    const float4 ta = *(const float4*)(w1t + c * 8);
    const float4 tb = *(const float4*)(w1t + c * 8 + 4);
#pragma unroll
    for (int i = 0; i < 4; ++i) {
      const float x = fmaxf(dot8(s[i], wa, wb) + cc, 0.f);
      z[i][0] += ta.x * x; z[i][1] += ta.y * x;
      z[i][2] += ta.z * x; z[i][3] += ta.w * x;
      z[i][4] += tb.x * x; z[i][5] += tb.y * x;
      z[i][6] += tb.z * x; z[i][7] += tb.w * x;
    }
  }
}

// ---------------------------------------------------------------------------
// K3: stats2 — prologue builds bn1-folded weights; main: 4 px/thread,
// z/z^2 partials -> part2[NB2][16].
__global__ __launch_bounds__(256) void k_stats2(
    const unsigned short* __restrict__ sB, const float* __restrict__ part1,
    const float* __restrict__ w0, const float* __restrict__ w1,
    const float* __restrict__ g0, const float* __restrict__ b0,
    float* __restrict__ part2) {
  __shared__ float red[256], totm[64], a1s[16], c1v[16], w0p[128], w1t[128];
  const int tid = threadIdx.x;
  tail_prologue(part1, w0, w1, g0, b0, red, totm, a1s, c1v, w0p, w1t);

  float sz[8], sz2[8];
#pragma unroll
  for (int o = 0; o < 8; ++o) { sz[o] = 0.f; sz2[o] = 0.f; }

  for (int g = blockIdx.x; g < NGRP4; g += NB2) {
    const uint4* src = (const uint4*)sB + (size_t)g * 1024 + tid;
    float s[4][8];
#pragma unroll
    for (int i = 0; i < 4; ++i) unpack8(src[i * 256], s[i]);
    float z[4][8];
    mlp_core(s, z, w0p, c1v, w1t);
#pragma unroll
    for (int i = 0; i < 4; ++i)
#pragma unroll
      for (int o = 0; o < 8; ++o) {
        sz[o] += z[i][o];
        sz2[o] += z[i][o] * z[i][o];
      }
  }
  const int wid = tid >> 6;
#pragma unroll
  for (int o = 0; o < 8; ++o) {
    float v = sz[o], v2 = sz2[o];
#pragma unroll
    for (int off = 32; off; off >>= 1) {
      v += __shfl_xor(v, off);
      v2 += __shfl_xor(v2, off);
    }
    if ((tid & 63) == 0) {
      red[wid * 16 + o] = v;
      red[wid * 16 + 8 + o] = v2;
    }
  }
  __syncthreads();
  if (tid < 16) {
    part2[blockIdx.x * 16 + tid] =
        red[tid] + red[16 + tid] + red[32 + tid] + red[48 + tid];
  }
}

// ---------------------------------------------------------------------------
// K4: final — prologue: bn1 weights + bn2 params; main: 4 px/thread,
// full MLP + sigmoid -> out.
__global__ __launch_bounds__(256) void k_final(
    const unsigned short* __restrict__ sB, const float* __restrict__ part1,
    const float* __restrict__ part2, const float* __restrict__ w0,
    const float* __restrict__ w1, const float* __restrict__ g0,
    const float* __restrict__ b0, const float* __restrict__ g1,
    const float* __restrict__ b1, const float* __restrict__ wsW,
    const float* __restrict__ bs, float* __restrict__ out) {
  __shared__ float red[256], totm[64], a1s[16], c1v[16], w0p[128], w1t[128];
  __shared__ float totz[16], w2s[32];  // w2s[o*4] = {a2, c2, ws, -}
  __shared__ float bssS;
  const int tid = threadIdx.x;
  tail_prologue(part1, w0, w1, g0, b0, red, totm, a1s, c1v, w0p, w1t);

  {  // reduce part2 (NB2 x 16)
    const int col = tid & 15, chk = tid >> 4;
    float a = 0.f;
    for (int r = chk; r < NB2; r += 16) a += part2[r * 16 + col];
    red[tid] = a;
  }
  __syncthreads();
  if (tid < 16) {
    float v = 0.f;
#pragma unroll
    for (int k = 0; k < 16; ++k) v += red[k * 16 + tid];
    totz[tid] = v;
  }
  if (tid == 32) bssS = bs[0];
  __syncthreads();
  if (tid < 8) {  // bn2
    const float invN = 1.f / (float)NPT;
    const float mean = totz[tid] * invN;
    const float var = totz[8 + tid] * invN - mean * mean;
    const float a = g1[tid] * rsqrtf(var + EPSV);
    w2s[tid * 4 + 0] = a;
    w2s[tid * 4 + 1] = b1[tid] - mean * a;
    w2s[tid * 4 + 2] = wsW[tid];
    w2s[tid * 4 + 3] = 0.f;
  }
  __syncthreads();

  const float bsr = bssS;
  for (int g = blockIdx.x; g < NGRP4; g += NBF) {
    const uint4* src = (const uint4*)sB + (size_t)g * 1024 + tid;
    float s[4][8];
#pragma unroll
    for (int i = 0; i < 4; ++i) unpack8(src[i * 256], s[i]);
    float z[4][8];
    mlp_core(s, z, w0p, c1v, w1t);

    float res[4];
#pragma unroll
    for (int i = 0; i < 4; ++i) res[i] = bsr;
#pragma unroll
    for (int o = 0; o < 8; ++o) {
      const float4 pr = *(const float4*)(w2s + o * 4);
#pragma unroll
      for (int i = 0; i < 4; ++i) {
        res[i] += pr.z * fmaxf(fmaf(pr.x, z[i][o], pr.y), 0.f);
      }
    }
    float* op = out + (size_t)g * 1024 + tid;
#pragma unroll
    for (int i = 0; i < 4; ++i) {
      op[i * 256] = 1.f / (1.f + __expf(-res[i]));
    }
  }
}

// ---------------------------------------------------------------------------
extern "C" void kernel_launch(void* const* d_in, const int* in_sizes, int n_in,
                              void* d_out, int out_size, void* d_ws,
                              size_t ws_size, hipStream_t stream) {
  const float* feat = (const float*)d_in[0];  // [2,64,256,320]
  const float* grid = (const float*)d_in[1];  // [2,2304,320,2]
  const float* w0 = (const float*)d_in[2];    // [16,8]
  const float* g0 = (const float*)d_in[3];
  const float* b0 = (const float*)d_in[4];
  const float* w1 = (const float*)d_in[5];    // [8,16]
  const float* g1 = (const float*)d_in[6];
  const float* b1 = (const float*)d_in[7];
  const float* wsW = (const float*)d_in[8];   // [1,8]
  const float* bs = (const float*)d_in[9];    // [1]
  float* out = (float*)d_out;

  float* wsf = (float*)d_ws;  // ~45 MB
  unsigned short* featB = (unsigned short*)(wsf + OFF_FEATB);
  unsigned short* sB    = (unsigned short*)(wsf + OFF_SB);
  float* part1 = wsf + OFF_P1;  // overlays featB (dead after k_sample)
  float* part2 = wsf + OFF_P2;

  k_transpose<<<Bc * (HWc / 64), 256, 0, stream>>>(feat, featB);
  k_sample<<<NBLK_S, 256, 0, stream>>>(grid, featB, sB);
  k_stats1<<<NB1, 256, 0, stream>>>(sB, part1);
  k_stats2<<<NB2, 256, 0, stream>>>(sB, part1, w0, w1, g0, b0, part2);
  k_final<<<NBF, 256, 0, stream>>>(sB, part1, part2, w0, w1, g0, b0, g1, b1,
                                   wsW, bs, out);
}

// Round 4
// 297.754 us; speedup vs baseline: 2.6046x; 1.4581x over previous
//
#include <hip/hip_runtime.h>
#include <math.h>

// FeatureWeightNet: grid_sample(bilinear,border) -> group correlation (G=8) ->
// MLP(8->16->8->1) with per-batch BN stats -> sigmoid.
// R11: root-cause fix for the R8/R9/R10 spill disease: any grid-stride loop
// whose body reads loop-invariant LDS weights gets LICM'd -> 272 weight
// floats promoted to registers -> VGPR 256 -> scratch spill storm.
// Structure now:
//  - NO loops in kernels that read LDS weights. stats2/final are straight-line
//    2 px/thread, grid = NPT/512 = 2880 blocks. Weights read once, die fast.
//  - Tiny 1-block reduce kernels (k_reduce1/k_reduce2) precompute BN-folded
//    params so the 2880-block kernels do no redundant reduction.
//  - stats1: moment-matrix identity (sum y^2 = w0^T (sum s s^T) w0); its loop
//    contains only global loads (no LICM target) — proven safe (R10: fine).
//  - No atomics anywhere. 7 dispatches.

constexpr int   Bc  = 2;
constexpr int   Cc  = 64;
constexpr int   Hc  = 256;
constexpr int   Wc  = 320;
constexpr int   NBc = 9;
constexpr int   HWc = Hc * Wc;            // 81920
constexpr int   NPIX = Bc * HWc;          // 163840
constexpr int   NPT  = Bc * NBc * HWc;    // 1474560 (= out_size)
constexpr float EPSV = 1e-5f;

constexpr int NBLK_S = NPIX / 32;         // 5120 sample blocks
constexpr int NB1    = 360;               // stats1 blocks (16 iters each)
constexpr int NBT    = NPT / 512;         // 2880 tail blocks (2 px/thread)

// workspace layout in float units (~44 MB)
constexpr size_t OFF_FEATB = 0;                               // NHWC bf16: NPIX*64 ushort
constexpr size_t OFF_SB    = OFF_FEATB + (size_t)NPIX * 32;   // s bf16: NPT*8 ushort
// scratch regions overlay featB (dead after k_sample):
constexpr size_t OFF_P1    = 0;                                // NB1*64 floats (44 used)
constexpr size_t OFF_P2    = OFF_P1 + (size_t)NB1 * 64;        // NBT*16 floats
constexpr size_t OFF_PAR1  = OFF_P2 + (size_t)NBT * 16;        // 272 floats: w0p[128], c1v[16], w1t[128]
constexpr size_t OFF_PAR2  = OFF_PAR1 + 272;                   // 33 floats: {a2,c2,ws}x8 + bs

__device__ __forceinline__ unsigned short f2bf_rne(float v) {
  unsigned int u = __float_as_uint(v);
  unsigned int r = (u + 0x7fffu + ((u >> 16) & 1u)) >> 16;
  return (unsigned short)r;
}
__device__ __forceinline__ void unpack8(uint4 u, float f[8]) {
  f[0] = __uint_as_float(u.x << 16);
  f[1] = __uint_as_float(u.x & 0xffff0000u);
  f[2] = __uint_as_float(u.y << 16);
  f[3] = __uint_as_float(u.y & 0xffff0000u);
  f[4] = __uint_as_float(u.z << 16);
  f[5] = __uint_as_float(u.z & 0xffff0000u);
  f[6] = __uint_as_float(u.w << 16);
  f[7] = __uint_as_float(u.w & 0xffff0000u);
}
__device__ __forceinline__ float dot8(const float s[8], float4 wa, float4 wb) {
  return s[0] * wa.x + s[1] * wa.y + s[2] * wa.z + s[3] * wa.w +
         s[4] * wb.x + s[5] * wb.y + s[6] * wb.z + s[7] * wb.w;
}

// ---------------------------------------------------------------------------
// K0: NCHW fp32 -> NHWC bf16 transpose.
__global__ __launch_bounds__(256) void k_transpose(
    const float* __restrict__ feat, unsigned short* __restrict__ featB) {
  __shared__ float lds[64][65];
  const int tid  = threadIdx.x;
  const int b    = blockIdx.x / (HWc / 64);
  const int tile = blockIdx.x % (HWc / 64);
  const int hw0  = tile * 64;
  const int p    = tid & 63;
  const int ty   = tid >> 6;  // 0..3

  const float* src = feat + (size_t)b * Cc * HWc + hw0 + p;
#pragma unroll
  for (int c0 = 0; c0 < 64; c0 += 4) {
    lds[c0 + ty][p] = src[(size_t)(c0 + ty) * HWc];
  }
  __syncthreads();
  const int ch = tid & 63;
  unsigned short* dst = featB + ((size_t)b * HWc + hw0) * 64 + ch;
#pragma unroll
  for (int p0 = 0; p0 < 64; p0 += 4) {
    dst[(size_t)(p0 + ty) * 64] = f2bf_rne(lds[ch][p0 + ty]);
  }
}

// ---------------------------------------------------------------------------
// K1: grid sample + group correlation.  PURE gather kernel (R2 structure —
// proven 3.9 TB/s).  UNCHANGED.
__global__ __launch_bounds__(256) void k_sample(
    const float* __restrict__ grid, const unsigned short* __restrict__ featB,
    unsigned short* __restrict__ sOut) {
  const int tid = threadIdx.x;
  const int cid = blockIdx.x * 32 + (tid >> 3);  // pixel id in [0, NPIX)
  const int j   = tid & 7;                       // group
  const int b   = cid / HWc;
  const int hw  = cid - b * HWc;
  const int h   = hw / Wc;
  const int w   = hw - h * Wc;

  const uint4* fbAll = (const uint4*)featB;
  const uint4 ur = fbAll[(size_t)cid * 8 + j];
  float r[8];
  unpack8(ur, r);

  const uint4* fb = fbAll + (size_t)b * HWc * 8;

#pragma unroll 3
  for (int n = 0; n < NBc; ++n) {
    const size_t gi = ((((size_t)b * NBc + n) * Hc + h) * Wc + w) * 2;
    const float2 g2 = *(const float2*)(grid + gi);
    float ix = ((g2.x + 1.f) * (float)Wc - 1.f) * 0.5f;
    float iy = ((g2.y + 1.f) * (float)Hc - 1.f) * 0.5f;
    ix = fminf(fmaxf(ix, 0.f), (float)(Wc - 1));
    iy = fminf(fmaxf(iy, 0.f), (float)(Hc - 1));
    const float x0f = floorf(ix), y0f = floorf(iy);
    const float fx = ix - x0f, fy = iy - y0f;
    const int x0 = (int)x0f, y0 = (int)y0f;
    const int x1 = min(x0 + 1, Wc - 1), y1 = min(y0 + 1, Hc - 1);
    const float w00 = (1.f - fx) * (1.f - fy);
    const float w01 = fx * (1.f - fy);
    const float w10 = (1.f - fx) * fy;
    const float w11 = fx * fy;

    const uint4 u00 = fb[(size_t)(y0 * Wc + x0) * 8 + j];
    const uint4 u01 = fb[(size_t)(y0 * Wc + x1) * 8 + j];
    const uint4 u10 = fb[(size_t)(y1 * Wc + x0) * 8 + j];
    const uint4 u11 = fb[(size_t)(y1 * Wc + x1) * 8 + j];
    float a[8], c[8], d[8], e[8];
    unpack8(u00, a);
    unpack8(u01, c);
    unpack8(u10, d);
    unpack8(u11, e);

    float s = 0.f;
#pragma unroll
    for (int k = 0; k < 8; ++k) {
      s += (w00 * a[k] + w01 * c[k] + w10 * d[k] + w11 * e[k]) * r[k];
    }
    s *= 0.125f;  // mean over C/G = 8

    const size_t pt = ((size_t)b * NBc + n) * HWc + hw;
    sOut[pt * 8 + j] = f2bf_rne(s);
  }
}

// ---------------------------------------------------------------------------
// K2: stats1 — moment matrix of s.  acc[0..7] = sum s_j; acc[8+tri(j,k)] =
// sum s_j*s_k (36).  No weights, no LDS in hot loop (loop is LICM-safe).
__global__ __launch_bounds__(256) void k_stats1(
    const unsigned short* __restrict__ sB, float* __restrict__ part1) {
  float acc[44];
#pragma unroll
  for (int i = 0; i < 44; ++i) acc[i] = 0.f;
  const int tid = threadIdx.x;
  const int stride = NB1 * 256;
  for (int p = blockIdx.x * 256 + tid; p < NPT; p += stride) {
    const uint4 su = ((const uint4*)sB)[p];
    float s[8];
    unpack8(su, s);
#pragma unroll
    for (int j = 0; j < 8; ++j) acc[j] += s[j];
#pragma unroll
    for (int j = 0; j < 8; ++j) {
#pragma unroll
      for (int k = 0; k <= j; ++k) {
        acc[8 + j * (j + 1) / 2 + k] += s[j] * s[k];
      }
    }
  }
  __shared__ float red[4 * 44];
  const int wid = tid >> 6;
#pragma unroll
  for (int i = 0; i < 44; ++i) {
    float v = acc[i];
#pragma unroll
    for (int off = 32; off; off >>= 1) v += __shfl_xor(v, off);
    if ((tid & 63) == 0) red[wid * 44 + i] = v;
  }
  __syncthreads();
  if (tid < 44) {
    part1[blockIdx.x * 64 + tid] =
        red[tid] + red[44 + tid] + red[88 + tid] + red[132 + tid];
  }
}

// ---------------------------------------------------------------------------
// K2b: reduce1 (1 block) — part1 -> moments -> bn1; write folded params:
// par1[0..127]  = w0p (a1-folded w0)
// par1[128..143]= c1v
// par1[144..271]= w1t (w1 transposed [c][o])
__global__ __launch_bounds__(256) void k_reduce1(
    const float* __restrict__ part1, const float* __restrict__ w0,
    const float* __restrict__ w1, const float* __restrict__ g0,
    const float* __restrict__ b0, float* __restrict__ par1) {
  __shared__ float red[256], totm[64], a1s[16];
  const int tid = threadIdx.x;
  {
    const int col = tid & 63, chk = tid >> 6;
    float a = 0.f;
    for (int r = chk; r < NB1; r += 4) a += part1[r * 64 + col];
    red[tid] = a;
  }
  __syncthreads();
  if (tid < 64)
    totm[tid] = red[tid] + red[64 + tid] + red[128 + tid] + red[192 + tid];
  __syncthreads();
  if (tid < 16) {
    float wr[8];
    float mean = 0.f, ey2 = 0.f;
#pragma unroll
    for (int j = 0; j < 8; ++j) {
      wr[j] = w0[tid * 8 + j];
      mean += wr[j] * totm[j];
    }
#pragma unroll
    for (int j = 0; j < 8; ++j) {
#pragma unroll
      for (int k = 0; k <= j; ++k) {
        const float v = wr[j] * wr[k] * totm[8 + j * (j + 1) / 2 + k];
        ey2 += (k == j) ? v : 2.f * v;
      }
    }
    const float invN = 1.f / (float)NPT;
    mean *= invN;
    ey2 *= invN;
    const float var = ey2 - mean * mean;
    const float a = g0[tid] * rsqrtf(var + EPSV);
    a1s[tid] = a;
    par1[128 + tid] = b0[tid] - mean * a;
  }
  __syncthreads();
  if (tid < 128) {
    par1[tid] = a1s[tid >> 3] * w0[tid];                 // w0p
    par1[144 + (tid & 15) * 8 + (tid >> 4)] = w1[tid];   // w1t
  }
}

// ---------------------------------------------------------------------------
// K3: stats2 — straight-line, 2 px/thread, NO loops (LICM-proof).
// Loads folded params into LDS; writes per-block z/z^2 partials.
__global__ __launch_bounds__(256) void k_stats2(
    const unsigned short* __restrict__ sB, const float* __restrict__ par1,
    float* __restrict__ part2) {
  __shared__ float w0ps[128], c1vs[16], w1ts[128];
  __shared__ float red[64];
  const int tid = threadIdx.x;
  if (tid < 128) {
    w0ps[tid] = par1[tid];
    w1ts[tid] = par1[144 + tid];
  }
  if (tid >= 128 && tid < 144) c1vs[tid - 128] = par1[tid];
  __syncthreads();

  const uint4* src = (const uint4*)sB + (size_t)blockIdx.x * 512 + tid;
  float s0[8], s1[8];
  unpack8(src[0], s0);
  unpack8(src[256], s1);

  float z0[8], z1[8];
#pragma unroll
  for (int o = 0; o < 8; ++o) { z0[o] = 0.f; z1[o] = 0.f; }
#pragma unroll
  for (int c = 0; c < 16; ++c) {
    const float4 wa = *(const float4*)(w0ps + c * 8);
    const float4 wb = *(const float4*)(w0ps + c * 8 + 4);
    const float cc = c1vs[c];
    const float4 ta = *(const float4*)(w1ts + c * 8);
    const float4 tb = *(const float4*)(w1ts + c * 8 + 4);
    const float xa = fmaxf(dot8(s0, wa, wb) + cc, 0.f);
    const float xb = fmaxf(dot8(s1, wa, wb) + cc, 0.f);
    z0[0] += ta.x * xa; z0[1] += ta.y * xa; z0[2] += ta.z * xa; z0[3] += ta.w * xa;
    z0[4] += tb.x * xa; z0[5] += tb.y * xa; z0[6] += tb.z * xa; z0[7] += tb.w * xa;
    z1[0] += ta.x * xb; z1[1] += ta.y * xb; z1[2] += ta.z * xb; z1[3] += ta.w * xb;
    z1[4] += tb.x * xb; z1[5] += tb.y * xb; z1[6] += tb.z * xb; z1[7] += tb.w * xb;
  }

  const int wid = tid >> 6;
#pragma unroll
  for (int o = 0; o < 8; ++o) {
    float v = z0[o] + z1[o];
    float v2 = z0[o] * z0[o] + z1[o] * z1[o];
#pragma unroll
    for (int off = 32; off; off >>= 1) {
      v += __shfl_xor(v, off);
      v2 += __shfl_xor(v2, off);
    }
    if ((tid & 63) == 0) {
      red[wid * 16 + o] = v;
      red[wid * 16 + 8 + o] = v2;
    }
  }
  __syncthreads();
  if (tid < 16) {
    part2[blockIdx.x * 16 + tid] =
        red[tid] + red[16 + tid] + red[32 + tid] + red[48 + tid];
  }
}

// ---------------------------------------------------------------------------
// K3b: reduce2 (1 block) — part2 -> bn2; write par2[o*4+{0,1,2}] = {a2,c2,ws},
// par2[32] = bs.
__global__ __launch_bounds__(256) void k_reduce2(
    const float* __restrict__ part2, const float* __restrict__ g1,
    const float* __restrict__ b1, const float* __restrict__ wsW,
    const float* __restrict__ bs, float* __restrict__ par2) {
  __shared__ float red[256], totz[16];
  const int tid = threadIdx.x;
  {
    const int col = tid & 15, chk = tid >> 4;
    float a = 0.f;
    for (int r = chk; r < NBT; r += 16) a += part2[r * 16 + col];
    red[tid] = a;
  }
  __syncthreads();
  if (tid < 16) {
    float v = 0.f;
#pragma unroll
    for (int k = 0; k < 16; ++k) v += red[k * 16 + tid];
    totz[tid] = v;
  }
  __syncthreads();
  if (tid < 8) {
    const float invN = 1.f / (float)NPT;
    const float mean = totz[tid] * invN;
    const float var = totz[8 + tid] * invN - mean * mean;
    const float a = g1[tid] * rsqrtf(var + EPSV);
    par2[tid * 4 + 0] = a;
    par2[tid * 4 + 1] = b1[tid] - mean * a;
    par2[tid * 4 + 2] = wsW[tid];
    par2[tid * 4 + 3] = 0.f;
  }
  if (tid == 8) par2[32] = bs[0];
}

// ---------------------------------------------------------------------------
// K4: final — straight-line, 2 px/thread, NO loops.  Full MLP + sigmoid.
__global__ __launch_bounds__(256) void k_final(
    const unsigned short* __restrict__ sB, const float* __restrict__ par1,
    const float* __restrict__ par2, float* __restrict__ out) {
  __shared__ float w0ps[128], c1vs[16], w1ts[128], w2s[33];
  const int tid = threadIdx.x;
  if (tid < 128) {
    w0ps[tid] = par1[tid];
    w1ts[tid] = par1[144 + tid];
  }
  if (tid >= 128 && tid < 144) c1vs[tid - 128] = par1[tid];
  if (tid >= 160 && tid < 193) w2s[tid - 160] = par2[tid - 160];
  __syncthreads();

  const uint4* src = (const uint4*)sB + (size_t)blockIdx.x * 512 + tid;
  float s0[8], s1[8];
  unpack8(src[0], s0);
  unpack8(src[256], s1);

  float z0[8], z1[8];
#pragma unroll
  for (int o = 0; o < 8; ++o) { z0[o] = 0.f; z1[o] = 0.f; }
#pragma unroll
  for (int c = 0; c < 16; ++c) {
    const float4 wa = *(const float4*)(w0ps + c * 8);
    const float4 wb = *(const float4*)(w0ps + c * 8 + 4);
    const float cc = c1vs[c];
    const float4 ta = *(const float4*)(w1ts + c * 8);
    const float4 tb = *(const float4*)(w1ts + c * 8 + 4);
    const float xa = fmaxf(dot8(s0, wa, wb) + cc, 0.f);
    const float xb = fmaxf(dot8(s1, wa, wb) + cc, 0.f);
    z0[0] += ta.x * xa; z0[1] += ta.y * xa; z0[2] += ta.z * xa; z0[3] += ta.w * xa;
    z0[4] += tb.x * xa; z0[5] += tb.y * xa; z0[6] += tb.z * xa; z0[7] += tb.w * xa;
    z1[0] += ta.x * xb; z1[1] += ta.y * xb; z1[2] += ta.z * xb; z1[3] += ta.w * xb;
    z1[4] += tb.x * xb; z1[5] += tb.y * xb; z1[6] += tb.z * xb; z1[7] += tb.w * xb;
  }

  float r0 = w2s[32], r1 = w2s[32];
#pragma unroll
  for (int o = 0; o < 8; ++o) {
    const float4 pr = *(const float4*)(w2s + o * 4);
    r0 += pr.z * fmaxf(fmaf(pr.x, z0[o], pr.y), 0.f);
    r1 += pr.z * fmaxf(fmaf(pr.x, z1[o], pr.y), 0.f);
  }
  float* op = out + (size_t)blockIdx.x * 512 + tid;
  op[0]   = 1.f / (1.f + __expf(-r0));
  op[256] = 1.f / (1.f + __expf(-r1));
}

// ---------------------------------------------------------------------------
extern "C" void kernel_launch(void* const* d_in, const int* in_sizes, int n_in,
                              void* d_out, int out_size, void* d_ws,
                              size_t ws_size, hipStream_t stream) {
  const float* feat = (const float*)d_in[0];  // [2,64,256,320]
  const float* grid = (const float*)d_in[1];  // [2,2304,320,2]
  const float* w0 = (const float*)d_in[2];    // [16,8]
  const float* g0 = (const float*)d_in[3];
  const float* b0 = (const float*)d_in[4];
  const float* w1 = (const float*)d_in[5];    // [8,16]
  const float* g1 = (const float*)d_in[6];
  const float* b1 = (const float*)d_in[7];
  const float* wsW = (const float*)d_in[8];   // [1,8]
  const float* bs = (const float*)d_in[9];    // [1]
  float* out = (float*)d_out;

  float* wsf = (float*)d_ws;  // ~45 MB
  unsigned short* featB = (unsigned short*)(wsf + OFF_FEATB);
  unsigned short* sB    = (unsigned short*)(wsf + OFF_SB);
  float* part1 = wsf + OFF_P1;   // overlays featB (dead after k_sample)
  float* part2 = wsf + OFF_P2;
  float* par1  = wsf + OFF_PAR1;
  float* par2  = wsf + OFF_PAR2;

  k_transpose<<<Bc * (HWc / 64), 256, 0, stream>>>(feat, featB);
  k_sample<<<NBLK_S, 256, 0, stream>>>(grid, featB, sB);
  k_stats1<<<NB1, 256, 0, stream>>>(sB, part1);
  k_reduce1<<<1, 256, 0, stream>>>(part1, w0, w1, g0, b0, par1);
  k_stats2<<<NBT, 256, 0, stream>>>(sB, par1, part2);
  k_reduce2<<<1, 256, 0, stream>>>(part2, g1, b1, wsW, bs, par2);
  k_final<<<NBT, 256, 0, stream>>>(sB, par1, par2, out);
}

// Round 5
// 245.311 us; speedup vs baseline: 3.1614x; 1.2138x over previous
//
#include <hip/hip_runtime.h>
#include <math.h>

// FeatureWeightNet: grid_sample(bilinear,border) -> group correlation (G=8) ->
// MLP(8->16->8->1) with per-batch BN stats -> sigmoid.
// R12: R11 cured the spill disease (no loops around LDS-weight reads ->
// no LICM register promotion). Remaining tail cost is LDS-latency-bound:
// 2 px/thread gave each c-iteration only ~38 VALU ops to hide ~120cy ds_read
// dependent latency. Changes:
//  - stats2/final: 4 px/thread STRAIGHT-LINE (no loops, LICM-proof), grid
//    NPT/1024 = 1440. ~76 VALU per c-step hides weight-read latency; LDS ops
//    per pixel halved. Live state s[4][8]+z[4][8]+weights ~= 110-130 VGPR.
//  - reduce1/reduce2: float4 partial reads (4x fewer latency-bound iters).
//  - transpose/sample/stats1 proven, untouched. No atomics. 7 dispatches.

constexpr int   Bc  = 2;
constexpr int   Cc  = 64;
constexpr int   Hc  = 256;
constexpr int   Wc  = 320;
constexpr int   NBc = 9;
constexpr int   HWc = Hc * Wc;            // 81920
constexpr int   NPIX = Bc * HWc;          // 163840
constexpr int   NPT  = Bc * NBc * HWc;    // 1474560 (= out_size)
constexpr float EPSV = 1e-5f;

constexpr int NBLK_S = NPIX / 32;         // 5120 sample blocks
constexpr int NB1    = 360;               // stats1 blocks (16 iters each)
constexpr int NBT4   = NPT / 1024;        // 1440 tail blocks (4 px/thread)

// workspace layout in float units (~44 MB)
constexpr size_t OFF_FEATB = 0;                               // NHWC bf16: NPIX*64 ushort
constexpr size_t OFF_SB    = OFF_FEATB + (size_t)NPIX * 32;   // s bf16: NPT*8 ushort
// scratch regions overlay featB (dead after k_sample):
constexpr size_t OFF_P1    = 0;                                // NB1*64 floats (44 used)
constexpr size_t OFF_P2    = OFF_P1 + (size_t)NB1 * 64;        // NBT4*16 floats
constexpr size_t OFF_PAR1  = OFF_P2 + (size_t)NBT4 * 16;       // 272 floats
constexpr size_t OFF_PAR2  = OFF_PAR1 + 272;                   // 33 floats

__device__ __forceinline__ unsigned short f2bf_rne(float v) {
  unsigned int u = __float_as_uint(v);
  unsigned int r = (u + 0x7fffu + ((u >> 16) & 1u)) >> 16;
  return (unsigned short)r;
}
__device__ __forceinline__ void unpack8(uint4 u, float f[8]) {
  f[0] = __uint_as_float(u.x << 16);
  f[1] = __uint_as_float(u.x & 0xffff0000u);
  f[2] = __uint_as_float(u.y << 16);
  f[3] = __uint_as_float(u.y & 0xffff0000u);
  f[4] = __uint_as_float(u.z << 16);
  f[5] = __uint_as_float(u.z & 0xffff0000u);
  f[6] = __uint_as_float(u.w << 16);
  f[7] = __uint_as_float(u.w & 0xffff0000u);
}
__device__ __forceinline__ float dot8(const float s[8], float4 wa, float4 wb) {
  return s[0] * wa.x + s[1] * wa.y + s[2] * wa.z + s[3] * wa.w +
         s[4] * wb.x + s[5] * wb.y + s[6] * wb.z + s[7] * wb.w;
}

// ---------------------------------------------------------------------------
// K0: NCHW fp32 -> NHWC bf16 transpose.
__global__ __launch_bounds__(256) void k_transpose(
    const float* __restrict__ feat, unsigned short* __restrict__ featB) {
  __shared__ float lds[64][65];
  const int tid  = threadIdx.x;
  const int b    = blockIdx.x / (HWc / 64);
  const int tile = blockIdx.x % (HWc / 64);
  const int hw0  = tile * 64;
  const int p    = tid & 63;
  const int ty   = tid >> 6;  // 0..3

  const float* src = feat + (size_t)b * Cc * HWc + hw0 + p;
#pragma unroll
  for (int c0 = 0; c0 < 64; c0 += 4) {
    lds[c0 + ty][p] = src[(size_t)(c0 + ty) * HWc];
  }
  __syncthreads();
  const int ch = tid & 63;
  unsigned short* dst = featB + ((size_t)b * HWc + hw0) * 64 + ch;
#pragma unroll
  for (int p0 = 0; p0 < 64; p0 += 4) {
    dst[(size_t)(p0 + ty) * 64] = f2bf_rne(lds[ch][p0 + ty]);
  }
}

// ---------------------------------------------------------------------------
// K1: grid sample + group correlation.  PURE gather kernel (R2 structure —
// proven 3.9 TB/s).  UNCHANGED.
__global__ __launch_bounds__(256) void k_sample(
    const float* __restrict__ grid, const unsigned short* __restrict__ featB,
    unsigned short* __restrict__ sOut) {
  const int tid = threadIdx.x;
  const int cid = blockIdx.x * 32 + (tid >> 3);  // pixel id in [0, NPIX)
  const int j   = tid & 7;                       // group
  const int b   = cid / HWc;
  const int hw  = cid - b * HWc;
  const int h   = hw / Wc;
  const int w   = hw - h * Wc;

  const uint4* fbAll = (const uint4*)featB;
  const uint4 ur = fbAll[(size_t)cid * 8 + j];
  float r[8];
  unpack8(ur, r);

  const uint4* fb = fbAll + (size_t)b * HWc * 8;

#pragma unroll 3
  for (int n = 0; n < NBc; ++n) {
    const size_t gi = ((((size_t)b * NBc + n) * Hc + h) * Wc + w) * 2;
    const float2 g2 = *(const float2*)(grid + gi);
    float ix = ((g2.x + 1.f) * (float)Wc - 1.f) * 0.5f;
    float iy = ((g2.y + 1.f) * (float)Hc - 1.f) * 0.5f;
    ix = fminf(fmaxf(ix, 0.f), (float)(Wc - 1));
    iy = fminf(fmaxf(iy, 0.f), (float)(Hc - 1));
    const float x0f = floorf(ix), y0f = floorf(iy);
    const float fx = ix - x0f, fy = iy - y0f;
    const int x0 = (int)x0f, y0 = (int)y0f;
    const int x1 = min(x0 + 1, Wc - 1), y1 = min(y0 + 1, Hc - 1);
    const float w00 = (1.f - fx) * (1.f - fy);
    const float w01 = fx * (1.f - fy);
    const float w10 = (1.f - fx) * fy;
    const float w11 = fx * fy;

    const uint4 u00 = fb[(size_t)(y0 * Wc + x0) * 8 + j];
    const uint4 u01 = fb[(size_t)(y0 * Wc + x1) * 8 + j];
    const uint4 u10 = fb[(size_t)(y1 * Wc + x0) * 8 + j];
    const uint4 u11 = fb[(size_t)(y1 * Wc + x1) * 8 + j];
    float a[8], c[8], d[8], e[8];
    unpack8(u00, a);
    unpack8(u01, c);
    unpack8(u10, d);
    unpack8(u11, e);

    float s = 0.f;
#pragma unroll
    for (int k = 0; k < 8; ++k) {
      s += (w00 * a[k] + w01 * c[k] + w10 * d[k] + w11 * e[k]) * r[k];
    }
    s *= 0.125f;  // mean over C/G = 8

    const size_t pt = ((size_t)b * NBc + n) * HWc + hw;
    sOut[pt * 8 + j] = f2bf_rne(s);
  }
}

// ---------------------------------------------------------------------------
// K2: stats1 — moment matrix of s.  acc[0..7] = sum s_j; acc[8+tri(j,k)] =
// sum s_j*s_k (36).  No weights, no LDS in hot loop (loop is LICM-safe).
__global__ __launch_bounds__(256) void k_stats1(
    const unsigned short* __restrict__ sB, float* __restrict__ part1) {
  float acc[44];
#pragma unroll
  for (int i = 0; i < 44; ++i) acc[i] = 0.f;
  const int tid = threadIdx.x;
  const int stride = NB1 * 256;
  for (int p = blockIdx.x * 256 + tid; p < NPT; p += stride) {
    const uint4 su = ((const uint4*)sB)[p];
    float s[8];
    unpack8(su, s);
#pragma unroll
    for (int j = 0; j < 8; ++j) acc[j] += s[j];
#pragma unroll
    for (int j = 0; j < 8; ++j) {
#pragma unroll
      for (int k = 0; k <= j; ++k) {
        acc[8 + j * (j + 1) / 2 + k] += s[j] * s[k];
      }
    }
  }
  __shared__ float red[4 * 44];
  const int wid = tid >> 6;
#pragma unroll
  for (int i = 0; i < 44; ++i) {
    float v = acc[i];
#pragma unroll
    for (int off = 32; off; off >>= 1) v += __shfl_xor(v, off);
    if ((tid & 63) == 0) red[wid * 44 + i] = v;
  }
  __syncthreads();
  if (tid < 44) {
    part1[blockIdx.x * 64 + tid] =
        red[tid] + red[44 + tid] + red[88 + tid] + red[132 + tid];
  }
}

// ---------------------------------------------------------------------------
// K2b: reduce1 (1 block) — part1 -> moments -> bn1; write folded params:
// par1[0..127] = w0p (a1-folded w0), par1[128..143] = c1v,
// par1[144..271] = w1t (w1 transposed [c][o]).
__global__ __launch_bounds__(256) void k_reduce1(
    const float* __restrict__ part1, const float* __restrict__ w0,
    const float* __restrict__ w1, const float* __restrict__ g0,
    const float* __restrict__ b0, float* __restrict__ par1) {
  __shared__ float red[1024], totm[64], a1s[16];
  const int tid = threadIdx.x;
  {  // float4 partial reads: 16 row-chunks x 16 col-quads
    const int cq = tid & 15, chk = tid >> 4;
    float4 a = make_float4(0.f, 0.f, 0.f, 0.f);
    for (int r = chk; r < NB1; r += 16) {
      const float4 v = *(const float4*)(part1 + r * 64 + cq * 4);
      a.x += v.x; a.y += v.y; a.z += v.z; a.w += v.w;
    }
    red[chk * 64 + cq * 4 + 0] = a.x;
    red[chk * 64 + cq * 4 + 1] = a.y;
    red[chk * 64 + cq * 4 + 2] = a.z;
    red[chk * 64 + cq * 4 + 3] = a.w;
  }
  __syncthreads();
  if (tid < 64) {
    float v = 0.f;
#pragma unroll
    for (int k = 0; k < 16; ++k) v += red[k * 64 + tid];
    totm[tid] = v;
  }
  __syncthreads();
  if (tid < 16) {
    float wr[8];
    float mean = 0.f, ey2 = 0.f;
#pragma unroll
    for (int j = 0; j < 8; ++j) {
      wr[j] = w0[tid * 8 + j];
      mean += wr[j] * totm[j];
    }
#pragma unroll
    for (int j = 0; j < 8; ++j) {
#pragma unroll
      for (int k = 0; k <= j; ++k) {
        const float v = wr[j] * wr[k] * totm[8 + j * (j + 1) / 2 + k];
        ey2 += (k == j) ? v : 2.f * v;
      }
    }
    const float invN = 1.f / (float)NPT;
    mean *= invN;
    ey2 *= invN;
    const float var = ey2 - mean * mean;
    const float a = g0[tid] * rsqrtf(var + EPSV);
    a1s[tid] = a;
    par1[128 + tid] = b0[tid] - mean * a;
  }
  __syncthreads();
  if (tid < 128) {
    par1[tid] = a1s[tid >> 3] * w0[tid];                 // w0p
    par1[144 + (tid & 15) * 8 + (tid >> 4)] = w1[tid];   // w1t
  }
}

// ---------------------------------------------------------------------------
// K3: stats2 — straight-line, 4 px/thread, NO loops (LICM-proof).
__global__ __launch_bounds__(256) void k_stats2(
    const unsigned short* __restrict__ sB, const float* __restrict__ par1,
    float* __restrict__ part2) {
  __shared__ float w0ps[128], c1vs[16], w1ts[128];
  __shared__ float red[64];
  const int tid = threadIdx.x;
  if (tid < 128) {
    w0ps[tid] = par1[tid];
    w1ts[tid] = par1[144 + tid];
  }
  if (tid >= 128 && tid < 144) c1vs[tid - 128] = par1[tid];
  __syncthreads();

  const uint4* src = (const uint4*)sB + (size_t)blockIdx.x * 1024 + tid;
  float s0[8], s1[8], s2[8], s3[8];
  unpack8(src[0], s0);
  unpack8(src[256], s1);
  unpack8(src[512], s2);
  unpack8(src[768], s3);

  float z0[8], z1[8], z2[8], z3[8];
#pragma unroll
  for (int o = 0; o < 8; ++o) { z0[o] = 0.f; z1[o] = 0.f; z2[o] = 0.f; z3[o] = 0.f; }
#pragma unroll
  for (int c = 0; c < 16; ++c) {
    const float4 wa = *(const float4*)(w0ps + c * 8);
    const float4 wb = *(const float4*)(w0ps + c * 8 + 4);
    const float cc = c1vs[c];
    const float4 ta = *(const float4*)(w1ts + c * 8);
    const float4 tb = *(const float4*)(w1ts + c * 8 + 4);
    const float xa = fmaxf(dot8(s0, wa, wb) + cc, 0.f);
    const float xb = fmaxf(dot8(s1, wa, wb) + cc, 0.f);
    const float xc = fmaxf(dot8(s2, wa, wb) + cc, 0.f);
    const float xd = fmaxf(dot8(s3, wa, wb) + cc, 0.f);
    z0[0] += ta.x * xa; z0[1] += ta.y * xa; z0[2] += ta.z * xa; z0[3] += ta.w * xa;
    z0[4] += tb.x * xa; z0[5] += tb.y * xa; z0[6] += tb.z * xa; z0[7] += tb.w * xa;
    z1[0] += ta.x * xb; z1[1] += ta.y * xb; z1[2] += ta.z * xb; z1[3] += ta.w * xb;
    z1[4] += tb.x * xb; z1[5] += tb.y * xb; z1[6] += tb.z * xb; z1[7] += tb.w * xb;
    z2[0] += ta.x * xc; z2[1] += ta.y * xc; z2[2] += ta.z * xc; z2[3] += ta.w * xc;
    z2[4] += tb.x * xc; z2[5] += tb.y * xc; z2[6] += tb.z * xc; z2[7] += tb.w * xc;
    z3[0] += ta.x * xd; z3[1] += ta.y * xd; z3[2] += ta.z * xd; z3[3] += ta.w * xd;
    z3[4] += tb.x * xd; z3[5] += tb.y * xd; z3[6] += tb.z * xd; z3[7] += tb.w * xd;
  }

  const int wid = tid >> 6;
#pragma unroll
  for (int o = 0; o < 8; ++o) {
    float v = (z0[o] + z1[o]) + (z2[o] + z3[o]);
    float v2 = (z0[o] * z0[o] + z1[o] * z1[o]) + (z2[o] * z2[o] + z3[o] * z3[o]);
#pragma unroll
    for (int off = 32; off; off >>= 1) {
      v += __shfl_xor(v, off);
      v2 += __shfl_xor(v2, off);
    }
    if ((tid & 63) == 0) {
      red[wid * 16 + o] = v;
      red[wid * 16 + 8 + o] = v2;
    }
  }
  __syncthreads();
  if (tid < 16) {
    part2[blockIdx.x * 16 + tid] =
        red[tid] + red[16 + tid] + red[32 + tid] + red[48 + tid];
  }
}

// ---------------------------------------------------------------------------
// K3b: reduce2 (1 block) — part2 -> bn2; par2[o*4+{0,1,2}] = {a2,c2,ws},
// par2[32] = bs.
__global__ __launch_bounds__(256) void k_reduce2(
    const float* __restrict__ part2, const float* __restrict__ g1,
    const float* __restrict__ b1, const float* __restrict__ wsW,
    const float* __restrict__ bs, float* __restrict__ par2) {
  __shared__ float red[1024], totz[16];
  const int tid = threadIdx.x;
  {  // float4 partial reads: 64 row-chunks x 4 col-quads
    const int cq = tid & 3, chk = tid >> 2;
    float4 a = make_float4(0.f, 0.f, 0.f, 0.f);
    for (int r = chk; r < NBT4; r += 64) {
      const float4 v = *(const float4*)(part2 + r * 16 + cq * 4);
      a.x += v.x; a.y += v.y; a.z += v.z; a.w += v.w;
    }
    red[chk * 16 + cq * 4 + 0] = a.x;
    red[chk * 16 + cq * 4 + 1] = a.y;
    red[chk * 16 + cq * 4 + 2] = a.z;
    red[chk * 16 + cq * 4 + 3] = a.w;
  }
  __syncthreads();
  if (tid < 16) {
    float v = 0.f;
#pragma unroll
    for (int k = 0; k < 64; ++k) v += red[k * 16 + tid];
    totz[tid] = v;
  }
  __syncthreads();
  if (tid < 8) {
    const float invN = 1.f / (float)NPT;
    const float mean = totz[tid] * invN;
    const float var = totz[8 + tid] * invN - mean * mean;
    const float a = g1[tid] * rsqrtf(var + EPSV);
    par2[tid * 4 + 0] = a;
    par2[tid * 4 + 1] = b1[tid] - mean * a;
    par2[tid * 4 + 2] = wsW[tid];
    par2[tid * 4 + 3] = 0.f;
  }
  if (tid == 8) par2[32] = bs[0];
}

// ---------------------------------------------------------------------------
// K4: final — straight-line, 4 px/thread, NO loops.  Full MLP + sigmoid.
__global__ __launch_bounds__(256) void k_final(
    const unsigned short* __restrict__ sB, const float* __restrict__ par1,
    const float* __restrict__ par2, float* __restrict__ out) {
  __shared__ float w0ps[128], c1vs[16], w1ts[128], w2s[33];
  const int tid = threadIdx.x;
  if (tid < 128) {
    w0ps[tid] = par1[tid];
    w1ts[tid] = par1[144 + tid];
  }
  if (tid >= 128 && tid < 144) c1vs[tid - 128] = par1[tid];
  if (tid >= 160 && tid < 193) w2s[tid - 160] = par2[tid - 160];
  __syncthreads();

  const uint4* src = (const uint4*)sB + (size_t)blockIdx.x * 1024 + tid;
  float s0[8], s1[8], s2[8], s3[8];
  unpack8(src[0], s0);
  unpack8(src[256], s1);
  unpack8(src[512], s2);
  unpack8(src[768], s3);

  float z0[8], z1[8], z2[8], z3[8];
#pragma unroll
  for (int o = 0; o < 8; ++o) { z0[o] = 0.f; z1[o] = 0.f; z2[o] = 0.f; z3[o] = 0.f; }
#pragma unroll
  for (int c = 0; c < 16; ++c) {
    const float4 wa = *(const float4*)(w0ps + c * 8);
    const float4 wb = *(const float4*)(w0ps + c * 8 + 4);
    const float cc = c1vs[c];
    const float4 ta = *(const float4*)(w1ts + c * 8);
    const float4 tb = *(const float4*)(w1ts + c * 8 + 4);
    const float xa = fmaxf(dot8(s0, wa, wb) + cc, 0.f);
    const float xb = fmaxf(dot8(s1, wa, wb) + cc, 0.f);
    const float xc = fmaxf(dot8(s2, wa, wb) + cc, 0.f);
    const float xd = fmaxf(dot8(s3, wa, wb) + cc, 0.f);
    z0[0] += ta.x * xa; z0[1] += ta.y * xa; z0[2] += ta.z * xa; z0[3] += ta.w * xa;
    z0[4] += tb.x * xa; z0[5] += tb.y * xa; z0[6] += tb.z * xa; z0[7] += tb.w * xa;
    z1[0] += ta.x * xb; z1[1] += ta.y * xb; z1[2] += ta.z * xb; z1[3] += ta.w * xb;
    z1[4] += tb.x * xb; z1[5] += tb.y * xb; z1[6] += tb.z * xb; z1[7] += tb.w * xb;
    z2[0] += ta.x * xc; z2[1] += ta.y * xc; z2[2] += ta.z * xc; z2[3] += ta.w * xc;
    z2[4] += tb.x * xc; z2[5] += tb.y * xc; z2[6] += tb.z * xc; z2[7] += tb.w * xc;
    z3[0] += ta.x * xd; z3[1] += ta.y * xd; z3[2] += ta.z * xd; z3[3] += ta.w * xd;
    z3[4] += tb.x * xd; z3[5] += tb.y * xd; z3[6] += tb.z * xd; z3[7] += tb.w * xd;
  }

  const float bsr = w2s[32];
  float r0 = bsr, r1 = bsr, r2 = bsr, r3 = bsr;
#pragma unroll
  for (int o = 0; o < 8; ++o) {
    const float4 pr = *(const float4*)(w2s + o * 4);
    r0 += pr.z * fmaxf(fmaf(pr.x, z0[o], pr.y), 0.f);
    r1 += pr.z * fmaxf(fmaf(pr.x, z1[o], pr.y), 0.f);
    r2 += pr.z * fmaxf(fmaf(pr.x, z2[o], pr.y), 0.f);
    r3 += pr.z * fmaxf(fmaf(pr.x, z3[o], pr.y), 0.f);
  }
  float* op = out + (size_t)blockIdx.x * 1024 + tid;
  op[0]   = 1.f / (1.f + __expf(-r0));
  op[256] = 1.f / (1.f + __expf(-r1));
  op[512] = 1.f / (1.f + __expf(-r2));
  op[768] = 1.f / (1.f + __expf(-r3));
}

// ---------------------------------------------------------------------------
extern "C" void kernel_launch(void* const* d_in, const int* in_sizes, int n_in,
                              void* d_out, int out_size, void* d_ws,
                              size_t ws_size, hipStream_t stream) {
  const float* feat = (const float*)d_in[0];  // [2,64,256,320]
  const float* grid = (const float*)d_in[1];  // [2,2304,320,2]
  const float* w0 = (const float*)d_in[2];    // [16,8]
  const float* g0 = (const float*)d_in[3];
  const float* b0 = (const float*)d_in[4];
  const float* w1 = (const float*)d_in[5];    // [8,16]
  const float* g1 = (const float*)d_in[6];
  const float* b1 = (const float*)d_in[7];
  const float* wsW = (const float*)d_in[8];   // [1,8]
  const float* bs = (const float*)d_in[9];    // [1]
  float* out = (float*)d_out;

  float* wsf = (float*)d_ws;  // ~45 MB
  unsigned short* featB = (unsigned short*)(wsf + OFF_FEATB);
  unsigned short* sB    = (unsigned short*)(wsf + OFF_SB);
  float* part1 = wsf + OFF_P1;   // overlays featB (dead after k_sample)
  float* part2 = wsf + OFF_P2;
  float* par1  = wsf + OFF_PAR1;
  float* par2  = wsf + OFF_PAR2;

  k_transpose<<<Bc * (HWc / 64), 256, 0, stream>>>(feat, featB);
  k_sample<<<NBLK_S, 256, 0, stream>>>(grid, featB, sB);
  k_stats1<<<NB1, 256, 0, stream>>>(sB, part1);
  k_reduce1<<<1, 256, 0, stream>>>(part1, w0, w1, g0, b0, par1);
  k_stats2<<<NBT4, 256, 0, stream>>>(sB, par1, part2);
  k_reduce2<<<1, 256, 0, stream>>>(part2, g1, b1, wsW, bs, par2);
  k_final<<<NBT4, 256, 0, stream>>>(sB, par1, par2, out);
}